// Round 9
// baseline (353.657 us; speedup 1.0000x reference)
//
#include <hip/hip_runtime.h>

#define NZ 1e-5f

__device__ __forceinline__ float fast_exp2(float x) {
#if __has_builtin(__builtin_amdgcn_exp2f)
    return __builtin_amdgcn_exp2f(x);   // v_exp_f32
#else
    return exp2f(x);
#endif
}

__device__ __forceinline__ float fast_log2(float x) {
#if __has_builtin(__builtin_amdgcn_logf)
    return __builtin_amdgcn_logf(x);    // v_log_f32 (base-2)
#else
    return log2f(x);
#endif
}

#define SBAR() __builtin_amdgcn_sched_barrier(0)

// R0-R6: wall = 365 * C, C ~= 723 cy/step, invariant under every memory/
// reorder/wave-split structure. R2 (NB=2, sequential lambdas) gave
// C_pair = C + 350: the compiler SERIALIZED the chains -- in-wave ILP was
// never actually tested. R8: NB=2 with the two basin chains HAND-INTERLEAVED
// statement-by-statement, pinned by sched_barrier(0) region fences.
// De-risked vehicle (R7 binary failed the container twice): NO LDS, NO
// global_load_lds, NO inline-asm waitcnt -- direct coalesced float2 loads
// with a 2-step register lookahead (12 floats; too small to collapse).
// Per-chain math is verbatim R6 (passed, absmax 0.0625).
__global__ __launch_bounds__(64, 1) void hbv_kernel(
    const float* __restrict__ precip,
    const float* __restrict__ temp,
    const float* __restrict__ pet,
    const float* __restrict__ phy,
    float* __restrict__ out,
    int G, int T)
{
    const int lane = threadIdx.x;            // 0..63
    const int g0   = blockIdx.x * 128;
    const int ga   = g0 + 2 * lane;          // chain A basin (even)
    const int gb   = ga + 1;                 // chain B basin
    const bool va = (ga < G), vb = (gb < G);
    const int gac = va ? ga : (G - 1);       // clamped (scalar param loads)
    const int gbc = vb ? gb : (G - 1);

    const float lo[14] = {1.0f, 50.0f, 0.05f, 0.01f, 0.001f, 0.2f, 0.0f,
                          0.0f, -2.5f, 0.5f, 0.0f, 0.0f, 0.3f, 0.0f};
    const float hi[14] = {6.0f, 1000.0f, 0.9f, 0.5f, 0.2f, 1.0f, 10.0f,
                          100.0f, 2.5f, 10.0f, 0.1f, 0.2f, 5.0f, 1.0f};
    float pa[14], pb[14];
#pragma unroll
    for (int i = 0; i < 14; ++i) {
        pa[i] = lo[i] + phy[gac * 14 + i] * (hi[i] - lo[i]);
        pb[i] = lo[i] + phy[gbc * 14 + i] * (hi[i] - lo[i]);
    }
    const float BETAa = pa[0], FCa = pa[1], K0a = pa[2], K1a = pa[3], K2a = pa[4];
    const float PERCpa = pa[6], UZLa = pa[7], TTa = pa[8], CFMAXa = pa[9];
    const float CWHa = pa[11], BETAETa = pa[12], Ca = pa[13];
    const float invFCa = 1.0f / FCa, invLPFCa = 1.0f / (pa[5] * FCa);
    const float CFRXa = pa[10] * pa[9];
    const float BETAb = pb[0], FCb = pb[1], K0b = pb[2], K1b = pb[3], K2b = pb[4];
    const float PERCpb = pb[6], UZLb = pb[7], TTb = pb[8], CFMAXb = pb[9];
    const float CWHb = pb[11], BETAETb = pb[12], Cb = pb[13];
    const float invFCb = 1.0f / FCb, invLPFCb = 1.0f / (pb[5] * FCb);
    const float CFRXb = pb[10] * pb[9];

    float SPa = NZ, MWa = NZ, SMa = NZ, SUZa = NZ, SLZa = NZ;
    float SPb = NZ, MWb = NZ, SMb = NZ, SUZb = NZ, SLZb = NZ;
    // carried values (exact relocations, verified R5/R6)
    float swca = fminf(fast_exp2(BETAa * fast_log2(SMa * invFCa)), 1.0f);
    float swcb = fminf(fast_exp2(BETAb * fast_log2(SMb * invFCb)), 1.0f);
    float CSLZa = Ca * SLZa, CSLZb = Cb * SLZb;

    // Interleaved paired step; per-chain op order/forms verbatim R6.
    auto step2 = [&](float pra, float tma, float pea,
                     float prb, float tmb, float peb) -> float2 {
        // ---- region 1: snow ----
        const float RAINa = (tma >= TTa) ? pra : 0.0f;
        const float RAINb = (tmb >= TTb) ? prb : 0.0f;
        const float SNOWa = pra - RAINa;
        const float SNOWb = prb - RAINb;
        SPa += SNOWa;                       SPb += SNOWb;
        const float melta = fminf(fmaxf(CFMAXa * (tma - TTa), 0.0f), SPa);
        const float meltb = fminf(fmaxf(CFMAXb * (tmb - TTb), 0.0f), SPb);
        MWa += melta;                       MWb += meltb;
        SPa -= melta;                       SPb -= meltb;
        const float refra = fminf(fmaxf(CFRXa * (TTa - tma), 0.0f), MWa);
        const float refrb = fminf(fmaxf(CFRXb * (TTb - tmb), 0.0f), MWb);
        SPa += refra;                       SPb += refrb;
        MWa -= refra;                       MWb -= refrb;
        const float tosoila = fmaxf(MWa - CWHa * SPa, 0.0f);
        const float tosoilb = fmaxf(MWb - CWHb * SPb, 0.0f);
        MWa -= tosoila;                     MWb -= tosoilb;
        const float rta = RAINa + tosoila;
        const float rtb = RAINb + tosoilb;
        SBAR();
        // ---- region 2: recharge + clamp ----
        const float rechargea = rta * swca;
        const float rechargeb = rtb * swcb;
        const float s_prea = SMa + rta - rechargea;
        const float s_preb = SMb + rtb - rechargeb;
        const float excessa = fmaxf(s_prea - FCa, 0.0f);
        const float excessb = fmaxf(s_preb - FCb, 0.0f);
        SMa = fminf(s_prea, FCa);
        SMb = fminf(s_preb, FCb);
        SBAR();
        // ---- region 3: ef pair + ET ----
        const float La = fast_log2(SMa * invLPFCa);
        const float Lb = fast_log2(SMb * invLPFCb);
        const float efa = fminf(fast_exp2(BETAETa * La), 1.0f);
        const float efb = fminf(fast_exp2(BETAETb * Lb), 1.0f);
        SMa = fmaxf(SMa - pea * efa, NZ);
        SMb = fmaxf(SMb - peb * efb, NZ);
        SBAR();
        // ---- region 4: capillary + next-sw log2 ----
        const float capa = fminf(SLZa, CSLZa * (1.0f - fminf(SMa * invFCa, 1.0f)));
        const float capb = fminf(SLZb, CSLZb * (1.0f - fminf(SMb * invFCb, 1.0f)));
        SMa = fmaxf(SMa + capa, NZ);
        SMb = fmaxf(SMb + capb, NZ);
        SLZa = fmaxf(SLZa - capa, NZ);
        SLZb = fmaxf(SLZb - capb, NZ);
        const float Lna = fast_log2(SMa * invFCa);
        const float Lnb = fast_log2(SMb * invFCb);
        SBAR();
        // ---- region 5: routing + carried tail ----
        SUZa += rechargea + excessa;
        SUZb += rechargeb + excessb;
        const float PERCa = fminf(SUZa, PERCpa);
        const float PERCb = fminf(SUZb, PERCpb);
        SUZa -= PERCa;                      SUZb -= PERCb;
        const float Q0a = K0a * fmaxf(SUZa - UZLa, 0.0f);
        const float Q0b = K0b * fmaxf(SUZb - UZLb, 0.0f);
        SUZa -= Q0a;                        SUZb -= Q0b;
        const float Q1a = K1a * SUZa;
        const float Q1b = K1b * SUZb;
        SUZa -= Q1a;                        SUZb -= Q1b;
        SLZa = fmaxf(SLZa + PERCa, 0.0f);
        SLZb = fmaxf(SLZb + PERCb, 0.0f);
        const float Q2a = K2a * SLZa;
        const float Q2b = K2b * SLZb;
        SLZa -= Q2a;                        SLZb -= Q2b;
        CSLZa = Ca * SLZa;                  CSLZb = Cb * SLZb;
        swca = fminf(fast_exp2(BETAa * Lna), 1.0f);
        swcb = fminf(fast_exp2(BETAb * Lnb), 1.0f);
        return make_float2(Q0a + Q1a + Q2a, Q0b + Q1b + Q2b);
    };

    if ((G & 1) == 0) {
        // ---- fast path: direct float2 loads, 2-step register lookahead ----
        const int gl = va ? ga : (G - 2);    // even & <= G-2: aligned, in-bounds

        auto ld3 = [&](int t, float2& P, float2& M, float2& E) {
            const int tc = (t < T) ? t : (T - 1);
            const size_t off = (size_t)tc * G + (size_t)gl;
            P = *(const float2*)&precip[off];
            M = *(const float2*)&temp[off];
            E = *(const float2*)&pet[off];
        };
        auto do_store = [&](int t, float2 q2) {
            const size_t idx = (size_t)t * G + (size_t)ga;
            if (vb)       *(float2*)&out[idx] = q2;
            else if (va)  out[idx] = q2.x;
        };

        float2 aP, aM, aE, bP, bM, bE;
        ld3(0, aP, aM, aE);
        ld3(1, bP, bM, bE);

        int t = 0;
        for (; t + 1 < T; t += 2) {
            float2 cP, cM, cE, dP, dM, dE;
            ld3(t + 2, cP, cM, cE);          // in flight across step2(a)
            SBAR();
            const float2 qa = step2(aP.x, aM.x, aE.x, aP.y, aM.y, aE.y);
            do_store(t, qa);
            ld3(t + 3, dP, dM, dE);          // in flight across step2(b)
            SBAR();
            const float2 qb = step2(bP.x, bM.x, bE.x, bP.y, bM.y, bE.y);
            do_store(t + 1, qb);
            aP = cP; aM = cM; aE = cE;
            bP = dP; bM = dM; bE = dE;
        }
        if (t < T) {                          // odd-T tail (t = T-1)
            const float2 qa = step2(aP.x, aM.x, aE.x, aP.y, aM.y, aE.y);
            do_store(t, qa);
        }
    } else {
        // ---- generic fallback (odd G; not taken for the bench shape) ----
        for (int t = 0; t < T; ++t) {
            const size_t ia = (size_t)t * G + gac;
            const size_t ib = (size_t)t * G + gbc;
            const float2 q2 = step2(precip[ia], temp[ia], pet[ia],
                                    precip[ib], temp[ib], pet[ib]);
            if (va) out[(size_t)t * G + ga] = q2.x;
            if (vb) out[(size_t)t * G + gb] = q2.y;
        }
    }
}

extern "C" void kernel_launch(void* const* d_in, const int* in_sizes, int n_in,
                              void* d_out, int out_size, void* d_ws, size_t ws_size,
                              hipStream_t stream) {
    const float* precip = (const float*)d_in[0];
    const float* temp   = (const float*)d_in[1];
    const float* pet    = (const float*)d_in[2];
    const float* phy    = (const float*)d_in[3];
    float* out = (float*)d_out;

    const int G = in_sizes[3] / 14;   // 50000
    const int T = in_sizes[0] / G;    // 365

    dim3 block(64);
    dim3 grid((G + 127) / 128);       // 391 blocks, 128 basins each
    hbv_kernel<<<grid, block, 0, stream>>>(precip, temp, pet, phy, out, G, T);
}